// Round 11
// baseline (261.842 us; speedup 1.0000x reference)
//
#include <hip/hip_runtime.h>
#include <cstdint>

using bf16x8  = __attribute__((ext_vector_type(8))) __bf16;
using f32x4   = __attribute__((ext_vector_type(4))) float;
using ushort8 = __attribute__((ext_vector_type(8))) unsigned short;

#define EPSN 1e-5f

__device__ __forceinline__ void gld16(const void* g, void* l) {
  __builtin_amdgcn_global_load_lds((const __attribute__((address_space(1))) void*)g,
                                   (__attribute__((address_space(3))) void*)l, 16, 0, 0);
}

__device__ __forceinline__ ushort f2bf(float f) {
  __bf16 h = (__bf16)f;
  return __builtin_bit_cast(unsigned short, h);
}
__device__ __forceinline__ float bf2f(ushort u) {
  union { uint32_t u; float f; } v; v.u = ((uint32_t)u) << 16; return v.f;
}

// ---------------------------------------------------------------------------
// k_pre: transx (5120, vectorized) | cvtW (3840) | pos (320) | bnp (2)
// ---------------------------------------------------------------------------
__global__ __launch_bounds__(256) void k_pre(const float* __restrict__ x0,
                                             const float* __restrict__ x1,
                                             const float* __restrict__ x2,
                                             const float* __restrict__ x3,
                                             const float* __restrict__ x4,
                                             const float* __restrict__ qW,
                                             const float* __restrict__ kW,
                                             const float* __restrict__ vW,
                                             const float* __restrict__ relH,
                                             const float* __restrict__ relW,
                                             const float* __restrict__ fg,
                                             const float* __restrict__ fb,
                                             const float* __restrict__ fm,
                                             const float* __restrict__ fv,
                                             const float* __restrict__ tg,
                                             const float* __restrict__ tb,
                                             const float* __restrict__ tm,
                                             const float* __restrict__ tv,
                                             ushort* __restrict__ xT,
                                             ushort* __restrict__ Wb,
                                             ushort* __restrict__ posb,
                                             float4* __restrict__ bnp) {
  __shared__ float tile[64][65];
  int bid = blockIdx.x;
  const int t = threadIdx.x;
  if (bid < 5120) {
    const int nt4 = bid & 3;  bid >>= 2;
    const int ct  = bid & 7;  bid >>= 3;
    const int b   = bid & 31; bid >>= 5;
    const int ix  = bid;
    const float* xs = ix == 0 ? x0 : ix == 1 ? x1 : ix == 2 ? x2 : ix == 3 ? x3 : x4;
    const float* src = xs + ((size_t)b * 512 + ct * 64) * 256 + nt4 * 64;
    const int col4 = (t & 15) * 4, r0 = t >> 4;
#pragma unroll
    for (int p = 0; p < 4; ++p) {
      int row = p * 16 + r0;
      float4 v = *(const float4*)(src + (size_t)row * 256 + col4);
      tile[row][col4 + 0] = v.x; tile[row][col4 + 1] = v.y;
      tile[row][col4 + 2] = v.z; tile[row][col4 + 3] = v.w;
    }
    __syncthreads();
    ushort* dst = xT + ((size_t)(ix * 32 + b) * 256 + nt4 * 64) * 512 + ct * 64;
    const int c8 = (t & 7) * 8, n0 = t >> 3;
#pragma unroll
    for (int p = 0; p < 2; ++p) {
      int nrow = p * 32 + n0;
      ushort8 o;
#pragma unroll
      for (int e = 0; e < 8; ++e) o[e] = f2bf(tile[c8 + e][nrow]);
      *(ushort8*)(dst + (size_t)nrow * 512 + c8) = o;
    }
  } else if (bid < 8960) {
    int idx = (bid - 5120) * 256 + t;
    int gi = idx * 4;
    int sel = gi / 1310720;
    int off = gi - sel * 1310720;
    const float* src = sel == 0 ? qW : (sel == 1 ? kW : vW);
    float4 vv = *(const float4*)(src + off);
    int h = off / 262144, rest = off - h * 262144;
    ushort4 o;
    o.x = f2bf(vv.x); o.y = f2bf(vv.y); o.z = f2bf(vv.z); o.w = f2bf(vv.w);
    *(ushort4*)(Wb + (size_t)(h * 3 + sel) * 262144 + rest) = o;
  } else if (bid < 9280) {
    int idx8 = (bid - 8960) * 256 + t;
    int e0 = idx8 * 8;
    int c0 = e0 & 511, m = (e0 >> 9) & 255, h = e0 >> 17;
    ushort8 o;
#pragma unroll
    for (int e = 0; e < 8; ++e) {
      int c = c0 + e;
      o[e] = f2bf(relH[((size_t)h * 512 + c) * 16 + (m >> 4)] +
                  relW[((size_t)h * 512 + c) * 16 + (m & 15)]);
    }
    *(ushort8*)(posb + e0) = o;
  } else {
    int o = (bid - 9280) * 256 + t;   // < 512
    float sf = fg[o] * rsqrtf(fv[o] + EPSN);
    float c1 = fb[o] - fm[o] * sf;
    float st = tg[o] * rsqrtf(tv[o] + EPSN);
    float c2 = tb[o] - tm[o] * st;
    bnp[o] = make_float4(sf, c1, st, c2);
  }
}

// ---------------------------------------------------------------------------
// k_qkv3: BM=128 x BN=256, BK=32, 8 waves (2M x 4N, per-wave 64x64, acc=64),
// ring-3 LDS (72KB), counted vmcnt(6), 2 blocks/CU. (R6/R8-proven.)
// ---------------------------------------------------------------------------
__global__ __launch_bounds__(512, 4) void k_qkv3(const ushort* __restrict__ Wb,
                                                 const ushort* __restrict__ xT,
                                                 const ushort* __restrict__ posb,
                                                 const float* __restrict__ qB,
                                                 const float* __restrict__ kB,
                                                 const float* __restrict__ vB,
                                                 ushort* __restrict__ qT,
                                                 ushort* __restrict__ kpT,
                                                 ushort* __restrict__ vv) {
  extern __shared__ ushort ls[];   // 72KB: A ring 3x8KB at 0, B ring 3x16KB at 12288
  const int t = threadIdx.x, lane = t & 63;
  const int w = t >> 6, wm = w >> 2, wn = w & 3, g = lane >> 4, l = lane & 15;
  int bid = blockIdx.x;
  bid = (bid & 7) * 240 + (bid >> 3);            // 1920 = 8*240 bijective
  const int h = bid / 384;
  const int r = bid % 384;

  const ushort* Ag;
  const ushort* Bg;
  const bool partA = r < 256;
  int pt = 0, nt = 0, mt = 0, ntv = 0;
  if (partA) {
    pt = r >> 2; nt = r & 3;
    Ag = xT + ((size_t)h * 8192 + pt * 128) * 512;
    Bg = Wb + ((size_t)(h * 3 + (nt >> 1)) * 512 + (nt & 1) * 256) * 512;
  } else {
    const int r2 = r - 256;
    mt = r2 >> 5; ntv = r2 & 31;
    Ag = Wb + ((size_t)(h * 3 + 2) * 512 + mt * 128) * 512;
    Bg = xT + ((size_t)h * 8192 + ntv * 256) * 512;
  }

  f32x4 acc[4][4];
#pragma unroll
  for (int i = 0; i < 4; ++i)
#pragma unroll
    for (int j = 0; j < 4; ++j) acc[i][j] = f32x4{0.f, 0.f, 0.f, 0.f};

#define QKV_STAGE(tt, slot)                                                    \
  {                                                                            \
    const int kb_ = (tt) * 32;                                                 \
    ushort* sa_ = ls + (slot) * 4096;                                          \
    ushort* sb_ = ls + 12288 + (slot) * 8192;                                  \
    {                                                                          \
      int q_ = t;                                                              \
      int row_ = q_ >> 2, s4_ = q_ & 3;                                        \
      int src_ = s4_ ^ ((row_ ^ (row_ >> 2)) & 3);                             \
      gld16(Ag + (size_t)row_ * 512 + kb_ + src_ * 8, sa_ + q_ * 8);           \
    }                                                                          \
    _Pragma("unroll")                                                          \
    for (int p_ = 0; p_ < 2; ++p_) {                                           \
      int q_ = p_ * 512 + t;                                                   \
      int row_ = q_ >> 2, s4_ = q_ & 3;                                        \
      int src_ = s4_ ^ ((row_ ^ (row_ >> 2)) & 3);                             \
      gld16(Bg + (size_t)row_ * 512 + kb_ + src_ * 8, sb_ + q_ * 8);           \
    }                                                                          \
  }

#define QKV_COMPUTE(slot)                                                      \
  {                                                                            \
    ushort* sa_ = ls + (slot) * 4096;                                          \
    ushort* sb_ = ls + 12288 + (slot) * 8192;                                  \
    bf16x8 af[4], bfv[4];                                                      \
    _Pragma("unroll")                                                          \
    for (int j_ = 0; j_ < 4; ++j_) {                                           \
      int rb_ = wn * 64 + j_ * 16 + l;                                         \
      int sb2_ = g ^ ((rb_ ^ (rb_ >> 2)) & 3);                                 \
      bfv[j_] = *(const bf16x8*)(sb_ + rb_ * 32 + sb2_ * 8);                   \
    }                                                                          \
    _Pragma("unroll")                                                          \
    for (int i_ = 0; i_ < 4; ++i_) {                                           \
      int ra_ = wm * 64 + i_ * 16 + l;                                         \
      int sa2_ = g ^ ((ra_ ^ (ra_ >> 2)) & 3);                                 \
      af[i_] = *(const bf16x8*)(sa_ + ra_ * 32 + sa2_ * 8);                    \
    }                                                                          \
    asm volatile("s_waitcnt lgkmcnt(0)" ::: "memory");                         \
    __builtin_amdgcn_sched_barrier(0);                                         \
    __builtin_amdgcn_s_setprio(1);                                             \
    _Pragma("unroll")                                                          \
    for (int i_ = 0; i_ < 4; ++i_)                                             \
      _Pragma("unroll")                                                        \
      for (int j_ = 0; j_ < 4; ++j_)                                           \
        acc[i_][j_] = __builtin_amdgcn_mfma_f32_16x16x32_bf16(af[i_], bfv[j_], \
                                                              acc[i_][j_], 0, 0, 0); \
    __builtin_amdgcn_s_setprio(0);                                             \
  }

  QKV_STAGE(0, 0);
  QKV_STAGE(1, 1);
  for (int tt = 0; tt < 16; ++tt) {
    __builtin_amdgcn_s_barrier();            // all waves done with slot (tt+2)%3
    if (tt < 14) { QKV_STAGE(tt + 2, (tt + 2) % 3); }
    __builtin_amdgcn_sched_barrier(0);
    if (tt < 14)       asm volatile("s_waitcnt vmcnt(6)" ::: "memory");
    else if (tt == 14) asm volatile("s_waitcnt vmcnt(3)" ::: "memory");
    else               asm volatile("s_waitcnt vmcnt(0)" ::: "memory");
    __builtin_amdgcn_s_barrier();            // everyone's stage(tt) landed
    __builtin_amdgcn_sched_barrier(0);
    QKV_COMPUTE(tt % 3);
  }
  __syncthreads();   // loop fully done before LDS reuse as C-bounce

  // C-bounce: 2 rounds of 64 rows, pad 260
  ushort(*Cs)[260] = (ushort(*)[260])ls;     // 64 x 260 x 2B = 33.3KB
  if (partA) {
    const bool isq = nt < 2;
    const float* bias = (isq ? qB : kB) + (size_t)h * 512 + (nt & 1) * 256;
    ushort* dst = isq ? qT : kpT;
    float bj[4];
#pragma unroll
    for (int j = 0; j < 4; ++j) bj[j] = bias[wn * 64 + j * 16 + l];
#pragma unroll
    for (int R = 0; R < 2; ++R) {
      if (wm == R) {
#pragma unroll
        for (int i = 0; i < 4; ++i)
#pragma unroll
          for (int j = 0; j < 4; ++j)
#pragma unroll
            for (int rr = 0; rr < 4; ++rr)
              Cs[i * 16 + g * 4 + rr][wn * 64 + j * 16 + l] = f2bf(acc[i][j][rr] + bj[j]);
      }
      __syncthreads();
#pragma unroll
      for (int it = 0; it < 4; ++it) {
        int lin = it * 512 + t;
        int row = lin >> 5, cc8 = (lin & 31) * 8;
        int pglob = pt * 128 + R * 64 + row;
        ushort8 cv = *(const ushort8*)&Cs[row][cc8];
        if (!isq) {
          ushort8 pv = *(const ushort8*)(posb + ((size_t)h * 256 + (pglob & 255)) * 512 +
                                         (nt & 1) * 256 + cc8);
#pragma unroll
          for (int e = 0; e < 8; ++e) cv[e] = f2bf(bf2f(cv[e]) + bf2f(pv[e]));
        }
        *(ushort8*)(dst + ((size_t)h * 8192 + pglob) * 512 + (nt & 1) * 256 + cc8) = cv;
      }
      if (R == 0) __syncthreads();
    }
  } else {
    const float* bias = vB + (size_t)h * 512 + mt * 128;
#pragma unroll
    for (int R = 0; R < 2; ++R) {
      if (wm == R) {
#pragma unroll
        for (int i = 0; i < 4; ++i) {
          float4 b4 = *(const float4*)(bias + R * 64 + i * 16 + g * 4);
#pragma unroll
          for (int j = 0; j < 4; ++j)
#pragma unroll
            for (int rr = 0; rr < 4; ++rr)
              Cs[i * 16 + g * 4 + rr][wn * 64 + j * 16 + l] =
                  f2bf(acc[i][j][rr] + ((const float*)&b4)[rr]);
        }
      }
      __syncthreads();
#pragma unroll
      for (int it = 0; it < 4; ++it) {
        int lin = it * 512 + t;
        int row = lin >> 5, cc8 = (lin & 31) * 8;
        int og = mt * 128 + R * 64 + row;
        ushort8 cv = *(const ushort8*)&Cs[row][cc8];
        *(ushort8*)(vv + (((size_t)(h * 32 + ntv)) * 512 + og) * 256 + cc8) = cv;
      }
      if (R == 0) __syncthreads();
    }
  }
#undef QKV_STAGE
#undef QKV_COMPUTE
}

// ---------------------------------------------------------------------------
// k_attn: fused energy+softmax (640) | cvtWconv (1024)
// ---------------------------------------------------------------------------
__global__ __launch_bounds__(256) void k_attn(const ushort* __restrict__ qT,
                                              const ushort* __restrict__ kpT,
                                              const float* __restrict__ fusW,
                                              ushort* __restrict__ attn,
                                              ushort* __restrict__ Wconv) {
  __shared__ ushort sm[20480];   // As 4096 | Bs 16384 ; reused as P[64][260]
  __shared__ float red[4][64];
  __shared__ float comb[64];
  int bid = blockIdx.x;
  const int t = threadIdx.x;
  if (bid >= 640) {
    int p = (bid - 640) * 256 + t;
    const float* src = fusW + (size_t)p * 9;
    float vv[9];
#pragma unroll
    for (int s = 0; s < 9; ++s) vv[s] = src[s];
#pragma unroll
    for (int s = 0; s < 9; ++s) Wconv[(size_t)s * 262144 + p] = f2bf(vv[s]);
    return;
  }
  bid = (bid & 7) * 80 + (bid >> 3);              // 640 = 8*80
  const int rt = bid & 3;
  const int hb = bid >> 2;
  ushort* As = sm;
  ushort* Bs = sm + 4096;
  const ushort* Ag = qT + ((size_t)hb * 256 + rt * 64) * 512;
  const ushort* Bg = kpT + (size_t)hb * 256 * 512;
  const int lane = t & 63, w = t >> 6, g = lane >> 4, l = lane & 15;

  f32x4 acc[4][4];
#pragma unroll
  for (int i = 0; i < 4; ++i)
#pragma unroll
    for (int j = 0; j < 4; ++j) acc[i][j] = f32x4{0.f, 0.f, 0.f, 0.f};

  for (int kt = 0; kt < 8; ++kt) {
    const int kbase = kt * 64;
#pragma unroll
    for (int p = 0; p < 2; ++p) {
      int q = p * 256 + t;
      int row = q >> 3, slot = q & 7, srcs = slot ^ (row & 7);
      gld16(Ag + (size_t)row * 512 + kbase + srcs * 8, As + (p * 256 + w * 64) * 8);
    }
#pragma unroll
    for (int p = 0; p < 8; ++p) {
      int q = p * 256 + t;
      int row = q >> 3, slot = q & 7, srcs = slot ^ (row & 7);
      gld16(Bg + (size_t)row * 512 + kbase + srcs * 8, Bs + (p * 256 + w * 64) * 8);
    }
    __syncthreads();
#pragma unroll
    for (int kk = 0; kk < 2; ++kk) {
      bf16x8 af[4], bfv[4];
#pragma unroll
      for (int i = 0; i < 4; ++i) {
        int ra = i * 16 + l;
        int sa = (kk * 4 + g) ^ (ra & 7);
        af[i] = *(const bf16x8*)(As + ra * 64 + sa * 8);
        int rb = w * 64 + i * 16 + l;
        int sb = (kk * 4 + g) ^ (rb & 7);
        bfv[i] = *(const bf16x8*)(Bs + rb * 64 + sb * 8);
      }
#pragma unroll
      for (int i = 0; i < 4; ++i)
#pragma unroll
        for (int j = 0; j < 4; ++j)
          acc[i][j] = __builtin_amdgcn_mfma_f32_16x16x32_bf16(af[i], bfv[j], acc[i][j], 0, 0, 0);
    }
    __syncthreads();
  }

#pragma unroll
  for (int i = 0; i < 4; ++i)
#pragma unroll
    for (int rr = 0; rr < 4; ++rr) {
      float v = fmaxf(fmaxf(acc[i][0][rr], acc[i][1][rr]), fmaxf(acc[i][2][rr], acc[i][3][rr]));
#pragma unroll
      for (int m = 1; m < 16; m <<= 1) v = fmaxf(v, __shfl_xor(v, m));
      if (l == 0) red[w][i * 16 + g * 4 + rr] = v;
    }
  __syncthreads();
  if (t < 64) comb[t] = fmaxf(fmaxf(red[0][t], red[1][t]), fmaxf(red[2][t], red[3][t]));
  __syncthreads();
#pragma unroll
  for (int i = 0; i < 4; ++i)
#pragma unroll
    for (int rr = 0; rr < 4; ++rr) {
      float mx = comb[i * 16 + g * 4 + rr];
      float s = 0.f;
#pragma unroll
      for (int j = 0; j < 4; ++j) {
        float e = expf(acc[i][j][rr] - mx);
        acc[i][j][rr] = e;
        s += e;
      }
#pragma unroll
      for (int m = 1; m < 16; m <<= 1) s += __shfl_xor(s, m);
      if (l == 0) red[w][i * 16 + g * 4 + rr] = s;
    }
  __syncthreads();
  if (t < 64) comb[t] = red[0][t] + red[1][t] + red[2][t] + red[3][t];
  __syncthreads();
  ushort(*P)[260] = (ushort(*)[260])sm;
#pragma unroll
  for (int i = 0; i < 4; ++i)
#pragma unroll
    for (int rr = 0; rr < 4; ++rr) {
      int row = i * 16 + g * 4 + rr;
      float inv = 1.f / comb[row];
#pragma unroll
      for (int j = 0; j < 4; ++j)
        P[row][w * 64 + j * 16 + l] = f2bf(acc[i][j][rr] * inv);
    }
  __syncthreads();
  ushort* Arow = attn + (size_t)hb * 65536 + (size_t)rt * 16384;
#pragma unroll
  for (int it = 0; it < 8; ++it) {
    int lin = it * 256 + t;
    int row = lin >> 5, c8 = (lin & 31) * 8;
    ushort8 cv = *(const ushort8*)&P[row][c8];
    *(ushort8*)(Arow + (size_t)row * 256 + c8) = cv;
  }
}

// ---------------------------------------------------------------------------
// k_pv: OT[n][c] = sum_m attn[n][m] * vv[c][m]. 128x128, BK=32, ring-3,
// counted vmcnt(8), 4 waves. (R6/R8-proven.)
// ---------------------------------------------------------------------------
__global__ __launch_bounds__(256, 4) void k_pv(const ushort* __restrict__ attn,
                                               const ushort* __restrict__ vv,
                                               ushort* __restrict__ OT) {
  __shared__ ushort pls[24576];   // 48KB: A ring 3x4096, B ring 3x4096 @12288
  const int t = threadIdx.x, lane = t & 63, w = t >> 6;
  const int wr = w >> 1, wc = w & 1, g = lane >> 4, l = lane & 15;
  int bid = blockIdx.x;
  bid = (bid & 7) * 160 + (bid >> 3);             // 1280 = 8*160
  const int nt = bid & 3; bid >>= 2;
  const int mt = bid & 1; bid >>= 1;
  const size_t hb = (size_t)bid;
  const ushort* Ag = attn + (hb * 256 + mt * 128) * 256;
  const ushort* Bg = vv + (hb * 512 + nt * 128) * 256;

  f32x4 acc[4][4];
#pragma unroll
  for (int i = 0; i < 4; ++i)
#pragma unroll
    for (int j = 0; j < 4; ++j) acc[i][j] = f32x4{0.f, 0.f, 0.f, 0.f};

#define PV_STAGE(tt, slot)                                                     \
  {                                                                            \
    const int kb_ = (tt) * 32;                                                 \
    ushort* sa_ = pls + (slot) * 4096;                                         \
    ushort* sb_ = pls + 12288 + (slot) * 4096;                                 \
    _Pragma("unroll")                                                          \
    for (int p_ = 0; p_ < 2; ++p_) {                                           \
      int q_ = p_ * 256 + t;                                                   \
      int row_ = q_ >> 2, s4_ = q_ & 3;                                        \
      int src_ = s4_ ^ ((row_ ^ (row_ >> 2)) & 3);                             \
      gld16(Ag + (size_t)row_ * 256 + kb_ + src_ * 8, sa_ + q_ * 8);           \
      gld16(Bg + (size_t)row_ * 256 + kb_ + src_ * 8, sb_ + q_ * 8);           \
    }                                                                          \
  }

#define PV_COMPUTE(slot)                                                       \
  {                                                                            \
    ushort* sa_ = pls + (slot) * 4096;                                         \
    ushort* sb_ = pls + 12288 + (slot) * 4096;                                 \
    bf16x8 af[4], bfv[4];                                                      \
    _Pragma("unroll")                                                          \
    for (int i_ = 0; i_ < 4; ++i_) {                                           \
      int ra_ = wr * 64 + i_ * 16 + l;                                         \
      int sa2_ = g ^ ((ra_ ^ (ra_ >> 2)) & 3);                                 \
      af[i_] = *(const bf16x8*)(sa_ + ra_ * 32 + sa2_ * 8);                    \
      int rb_ = wc * 64 + i_ * 16 + l;                                         \
      int sb2_ = g ^ ((rb_ ^ (rb_ >> 2)) & 3);                                 \
      bfv[i_] = *(const bf16x8*)(sb_ + rb_ * 32 + sb2_ * 8);                   \
    }                                                                          \
    asm volatile("s_waitcnt lgkmcnt(0)" ::: "memory");                         \
    __builtin_amdgcn_sched_barrier(0);                                         \
    __builtin_amdgcn_s_setprio(1);                                             \
    _Pragma("unroll")                                                          \
    for (int i_ = 0; i_ < 4; ++i_)                                             \
      _Pragma("unroll")                                                        \
      for (int j_ = 0; j_ < 4; ++j_)                                           \
        acc[i_][j_] = __builtin_amdgcn_mfma_f32_16x16x32_bf16(af[i_], bfv[j_], \
                                                              acc[i_][j_], 0, 0, 0); \
    __builtin_amdgcn_s_setprio(0);                                             \
  }

  PV_STAGE(0, 0);
  PV_STAGE(1, 1);
  for (int tt = 0; tt < 8; ++tt) {
    __builtin_amdgcn_s_barrier();
    if (tt < 6) { PV_STAGE(tt + 2, (tt + 2) % 3); }
    __builtin_amdgcn_sched_barrier(0);
    if (tt < 6)       asm volatile("s_waitcnt vmcnt(8)" ::: "memory");
    else if (tt == 6) asm volatile("s_waitcnt vmcnt(4)" ::: "memory");
    else              asm volatile("s_waitcnt vmcnt(0)" ::: "memory");
    __builtin_amdgcn_s_barrier();
    __builtin_amdgcn_sched_barrier(0);
    PV_COMPUTE(tt % 3);
  }
  __syncthreads();

  ushort(*Cs)[148] = (ushort(*)[148])pls;   // 128 x 148 x 2B = 37.9KB
#pragma unroll
  for (int i = 0; i < 4; ++i)
#pragma unroll
    for (int j = 0; j < 4; ++j)
#pragma unroll
      for (int rr = 0; rr < 4; ++rr)
        Cs[wr * 64 + i * 16 + g * 4 + rr][wc * 64 + j * 16 + l] = f2bf(acc[i][j][rr]);
  __syncthreads();
#pragma unroll
  for (int it = 0; it < 8; ++it) {
    int lin = it * 256 + t;
    int row = lin >> 4, cc = (lin & 15) * 8;
    ushort8 cv = *(const ushort8*)&Cs[row][cc];
    *(ushort8*)(OT + (hb * 256 + mt * 128 + row) * 512 + nt * 128 + cc) = cv;
  }
#undef PV_STAGE
#undef PV_COMPUTE
}

// ---------------------------------------------------------------------------
// k_weights: wave-per-pixel, msw staged once per block in LDS
// ---------------------------------------------------------------------------
__global__ __launch_bounds__(256) void k_weights(const ushort* __restrict__ OT,
                                                 const float* __restrict__ mswW,
                                                 const float* __restrict__ mg,
                                                 const float* __restrict__ mb,
                                                 const float* __restrict__ mm,
                                                 const float* __restrict__ mv,
                                                 ushort* __restrict__ xmsT) {
  __shared__ float msw[10240];
  const int t = threadIdx.x, lane = t & 63, w = t >> 6;
#pragma unroll
  for (int it = 0; it < 10; ++it) {
    int idx = it * 1024 + t * 4;
    *(float4*)(msw + idx) = *(const float4*)(mswW + idx);
  }
  __syncthreads();
  const size_t pix = (size_t)blockIdx.x * 4 + w;
  float o[5][2][4];
#pragma unroll
  for (int h = 0; h < 5; ++h)
#pragma unroll
    for (int hf = 0; hf < 2; ++hf) {
      ushort4 v = *(const ushort4*)(OT + ((size_t)h * 8192 + pix) * 512 + hf * 256 + lane * 4);
      o[h][hf][0] = bf2f(v.x); o[h][hf][1] = bf2f(v.y);
      o[h][hf][2] = bf2f(v.z); o[h][hf][3] = bf2f(v.w);
    }
  float a[4] = {0.f, 0.f, 0.f, 0.f};
#pragma unroll
  for (int j = 0; j < 4; ++j)
#pragma unroll
    for (int h = 0; h < 5; ++h)
#pragma unroll
      for (int hf = 0; hf < 2; ++hf) {
        float4 m4 = *(const float4*)(msw + j * 2560 + h * 512 + hf * 256 + lane * 4);
        a[j] += m4.x * o[h][hf][0] + m4.y * o[h][hf][1] +
                m4.z * o[h][hf][2] + m4.w * o[h][hf][3];
      }
#pragma unroll
  for (int m = 1; m < 64; m <<= 1) {
    a[0] += __shfl_xor(a[0], m); a[1] += __shfl_xor(a[1], m);
    a[2] += __shfl_xor(a[2], m); a[3] += __shfl_xor(a[3], m);
  }
  float wj[4];
#pragma unroll
  for (int j = 0; j < 4; ++j) {
    float val = (a[j] - mm[j]) * (mg[j] * rsqrtf(mv[j] + EPSN)) + mb[j];
    wj[j] = 1.f / (1.f + expf(-val));
  }
#pragma unroll
  for (int hf = 0; hf < 2; ++hf) {
    float r0 = wj[0] * o[0][hf][0] + wj[1] * o[1][hf][0] + wj[2] * o[2][hf][0] + wj[3] * o[3][hf][0] + o[4][hf][0];
    float r1 = wj[0] * o[0][hf][1] + wj[1] * o[1][hf][1] + wj[2] * o[2][hf][1] + wj[3] * o[3][hf][1] + o[4][hf][1];
    float r2 = wj[0] * o[0][hf][2] + wj[1] * o[1][hf][2] + wj[2] * o[2][hf][2] + wj[3] * o[3][hf][2] + o[4][hf][2];
    float r3 = wj[0] * o[0][hf][3] + wj[1] * o[1][hf][3] + wj[2] * o[2][hf][3] + wj[3] * o[3][hf][3] + o[4][hf][3];
    ushort4 pk; pk.x = f2bf(r0); pk.y = f2bf(r1); pk.z = f2bf(r2); pk.w = f2bf(r3);
    *(ushort4*)(xmsT + pix * 512 + hf * 256 + lane * 4) = pk;
  }
}

// ---------------------------------------------------------------------------
// conv3x3 full-K, 1024 blocks (o-tile 32, n-tile 128), 256 threads (4 waves,
// per-wave 32o x 32n). All 9 (dy,dx) weight slices staged per cb -> only 2
// barriers per cb (16/block vs 48). Fused bn_fus+relu+residual+bn_top+relu.
// ---------------------------------------------------------------------------
__global__ __launch_bounds__(256) void k_conv(const ushort* __restrict__ Wconv,
                                              const ushort* __restrict__ xmsT,
                                              const float* __restrict__ x,
                                              const float4* __restrict__ bnp,
                                              float* __restrict__ out) {
  __shared__ ushort As9[9 * 2048];       // 36KB: 9 (dy*3+dx) x (32 o x 64 c)
  __shared__ ushort xp[180 * 76];        // 26.7KB (pad 76)
  int bid = blockIdx.x;
  bid = (bid & 7) * 128 + (bid >> 3);             // 1024 = 8*128 bijective
  const int ntl = bid & 1;  bid >>= 1;
  const int mt  = bid & 15; bid >>= 4;            // o-tile of 32
  const int bb  = bid;                            // 0..31
  const int y0 = ntl * 8;
  const int t = threadIdx.x, lane = t & 63;
  const int w = t >> 6, g = lane >> 4, l = lane & 15;
  f32x4 acc[2][2];
#pragma unroll
  for (int i = 0; i < 2; ++i)
#pragma unroll
    for (int j = 0; j < 2; ++j) acc[i][j] = f32x4{0.f, 0.f, 0.f, 0.f};

  for (int cb = 0; cb < 8; ++cb) {
    __syncthreads();   // protect xp/As9 from previous-round readers
    for (int u = t; u < 1440; u += 256) {
      int slot = u & 7;
      int xpi = (u >> 3) % 18;
      int rl = u / 144;
      int yg = y0 - 1 + rl, xg = xpi - 1;
      uint4 val = make_uint4(0, 0, 0, 0);
      if (yg >= 0 && yg < 16 && (unsigned)xg < 16u)
        val = *(const uint4*)(xmsT + ((size_t)bb * 256 + yg * 16 + xg) * 512 + cb * 64 + slot * 8);
      *(uint4*)(xp + (rl * 18 + xpi) * 76 + slot * 8) = val;
    }
    {
      int row = t >> 3, slot = t & 7, srcs = slot ^ (row & 7);
#pragma unroll
      for (int s = 0; s < 9; ++s)
        gld16(Wconv + ((size_t)s * 512 + mt * 32 + row) * 512 + cb * 64 + srcs * 8,
              As9 + s * 2048 + t * 8);
    }
    __syncthreads();   // all 9 W slices + xp visible
    for (int dy = 0; dy < 3; ++dy)
#pragma unroll
      for (int dx = 0; dx < 3; ++dx)
#pragma unroll
        for (int kk = 0; kk < 2; ++kk) {
          bf16x8 af[2], bfv[2];
#pragma unroll
          for (int j = 0; j < 2; ++j) {
            int nl = w * 32 + j * 16 + l;
            int pp = ((nl >> 4) + dy) * 18 + (nl & 15) + dx;
            bfv[j] = *(const bf16x8*)(xp + pp * 76 + (kk * 4 + g) * 8);
          }
#pragma unroll
          for (int i = 0; i < 2; ++i) {
            int ra = i * 16 + l;
            int sa = (kk * 4 + g) ^ (ra & 7);
            af[i] = *(const bf16x8*)(As9 + (dy * 3 + dx) * 2048 + ra * 64 + sa * 8);
          }
#pragma unroll
          for (int i = 0; i < 2; ++i)
#pragma unroll
            for (int j = 0; j < 2; ++j)
              acc[i][j] = __builtin_amdgcn_mfma_f32_16x16x32_bf16(af[i], bfv[j], acc[i][j], 0, 0, 0);
        }
  }
  // fused epilogue: z = max(acc*sf+c1,0); out = max((z+x)*st+c2, 0)
  const int o0 = mt * 32;
#pragma unroll
  for (int i = 0; i < 2; ++i)
#pragma unroll
    for (int rr = 0; rr < 4; ++rr) {
      int o = o0 + i * 16 + g * 4 + rr;
      float4 p4 = bnp[o];
#pragma unroll
      for (int j = 0; j < 2; ++j) {
        int n = ntl * 128 + w * 32 + j * 16 + l;
        size_t idx = ((size_t)bb * 512 + o) * 256 + n;
        float z = fmaxf(acc[i][j][rr] * p4.x + p4.y, 0.f);
        out[idx] = fmaxf((z + x[idx]) * p4.z + p4.w, 0.f);
      }
    }
}

// ---------------------------------------------------------------------------
extern "C" void kernel_launch(void* const* d_in, const int* in_sizes, int n_in,
                              void* d_out, int out_size, void* d_ws, size_t ws_size,
                              hipStream_t stream) {
  const float* x0   = (const float*)d_in[0];
  const float* x1   = (const float*)d_in[1];
  const float* x2   = (const float*)d_in[2];
  const float* x3   = (const float*)d_in[3];
  const float* x4   = (const float*)d_in[4];
  const float* qW   = (const float*)d_in[5];
  const float* qB   = (const float*)d_in[6];
  const float* kW   = (const float*)d_in[7];
  const float* kB   = (const float*)d_in[8];
  const float* vW   = (const float*)d_in[9];
  const float* vB   = (const float*)d_in[10];
  const float* relH = (const float*)d_in[11];
  const float* relW = (const float*)d_in[12];
  const float* mswW = (const float*)d_in[13];
  const float* msg  = (const float*)d_in[14];
  const float* msb  = (const float*)d_in[15];
  const float* msm  = (const float*)d_in[16];
  const float* msv  = (const float*)d_in[17];
  const float* fusW = (const float*)d_in[18];
  const float* fg   = (const float*)d_in[19];
  const float* fb   = (const float*)d_in[20];
  const float* fm   = (const float*)d_in[21];
  const float* fv   = (const float*)d_in[22];
  const float* tg   = (const float*)d_in[23];
  const float* tb   = (const float*)d_in[24];
  const float* tm   = (const float*)d_in[25];
  const float* tv   = (const float*)d_in[26];

  if (ws_size < 180355072ull) return;
  char* ws = (char*)d_ws;
  ushort* xT    = (ushort*)(ws + 0);           // R0 until k_qkv3
  ushort* attn  = (ushort*)(ws + 0);           // R0[0..21MB) after k_qkv3
  ushort* Wconv = (ushort*)(ws + 20971520);    // R0[21..25.7MB) after k_qkv3
  ushort* qT    = (ushort*)(ws + 41943040);    // R1 until k_attn
  ushort* xmsT  = (ushort*)(ws + 41943040);    // R1[0..8.4MB) after k_attn
  ushort* kpT   = (ushort*)(ws + 83886080);    // R2 until k_attn
  ushort* OT    = (ushort*)(ws + 83886080);    // R2 after k_attn
  ushort* vv    = (ushort*)(ws + 125829120);   // R3 until k_pv
  ushort* Wb    = (ushort*)(ws + 167772160);   // R4
  ushort* posb  = (ushort*)(ws + 175636480);   // R4 + 7.5MB (1.25MB)
  float4* bnp   = (float4*)(ws + 176947200);   // 8KB

  hipFuncSetAttribute((const void*)k_qkv3,
                      hipFuncAttributeMaxDynamicSharedMemorySize, 73728);

  k_pre    <<<9282, 256, 0, stream>>>(x0, x1, x2, x3, x4, qW, kW, vW, relH, relW,
                                      fg, fb, fm, fv, tg, tb, tm, tv,
                                      xT, Wb, posb, (float4*)bnp);
  k_qkv3   <<<1920, 512, 73728, stream>>>(Wb, xT, posb, qB, kB, vB, qT, kpT, vv);
  k_attn   <<<1664, 256, 0, stream>>>(qT, kpT, fusW, attn, Wconv);
  k_pv     <<<1280, 256, 0, stream>>>(attn, vv, OT);
  k_weights<<<2048, 256, 0, stream>>>(OT, mswW, msg, msb, msm, msv, xmsT);
  k_conv   <<<1024, 256, 0, stream>>>(Wconv, xmsT, x4, bnp, (float*)d_out);
}

// Round 12
// 246.222 us; speedup vs baseline: 1.0634x; 1.0634x over previous
//
#include <hip/hip_runtime.h>
#include <cstdint>

using bf16x8  = __attribute__((ext_vector_type(8))) __bf16;
using f32x4   = __attribute__((ext_vector_type(4))) float;
using ushort8 = __attribute__((ext_vector_type(8))) unsigned short;

#define EPSN 1e-5f

__device__ __forceinline__ void gld16(const void* g, void* l) {
  __builtin_amdgcn_global_load_lds((const __attribute__((address_space(1))) void*)g,
                                   (__attribute__((address_space(3))) void*)l, 16, 0, 0);
}

__device__ __forceinline__ ushort f2bf(float f) {
  __bf16 h = (__bf16)f;
  return __builtin_bit_cast(unsigned short, h);
}
__device__ __forceinline__ float bf2f(ushort u) {
  union { uint32_t u; float f; } v; v.u = ((uint32_t)u) << 16; return v.f;
}

// ---------------------------------------------------------------------------
// k_pre: transx (5120, vectorized) | cvtW (3840) | pos (320) | bnp (2)
// ---------------------------------------------------------------------------
__global__ __launch_bounds__(256) void k_pre(const float* __restrict__ x0,
                                             const float* __restrict__ x1,
                                             const float* __restrict__ x2,
                                             const float* __restrict__ x3,
                                             const float* __restrict__ x4,
                                             const float* __restrict__ qW,
                                             const float* __restrict__ kW,
                                             const float* __restrict__ vW,
                                             const float* __restrict__ relH,
                                             const float* __restrict__ relW,
                                             const float* __restrict__ fg,
                                             const float* __restrict__ fb,
                                             const float* __restrict__ fm,
                                             const float* __restrict__ fv,
                                             const float* __restrict__ tg,
                                             const float* __restrict__ tb,
                                             const float* __restrict__ tm,
                                             const float* __restrict__ tv,
                                             ushort* __restrict__ xT,
                                             ushort* __restrict__ Wb,
                                             ushort* __restrict__ posb,
                                             float4* __restrict__ bnp) {
  __shared__ float tile[64][65];
  int bid = blockIdx.x;
  const int t = threadIdx.x;
  if (bid < 5120) {
    const int nt4 = bid & 3;  bid >>= 2;
    const int ct  = bid & 7;  bid >>= 3;
    const int b   = bid & 31; bid >>= 5;
    const int ix  = bid;
    const float* xs = ix == 0 ? x0 : ix == 1 ? x1 : ix == 2 ? x2 : ix == 3 ? x3 : x4;
    const float* src = xs + ((size_t)b * 512 + ct * 64) * 256 + nt4 * 64;
    const int col4 = (t & 15) * 4, r0 = t >> 4;
#pragma unroll
    for (int p = 0; p < 4; ++p) {
      int row = p * 16 + r0;
      float4 v = *(const float4*)(src + (size_t)row * 256 + col4);
      tile[row][col4 + 0] = v.x; tile[row][col4 + 1] = v.y;
      tile[row][col4 + 2] = v.z; tile[row][col4 + 3] = v.w;
    }
    __syncthreads();
    ushort* dst = xT + ((size_t)(ix * 32 + b) * 256 + nt4 * 64) * 512 + ct * 64;
    const int c8 = (t & 7) * 8, n0 = t >> 3;
#pragma unroll
    for (int p = 0; p < 2; ++p) {
      int nrow = p * 32 + n0;
      ushort8 o;
#pragma unroll
      for (int e = 0; e < 8; ++e) o[e] = f2bf(tile[c8 + e][nrow]);
      *(ushort8*)(dst + (size_t)nrow * 512 + c8) = o;
    }
  } else if (bid < 8960) {
    int idx = (bid - 5120) * 256 + t;
    int gi = idx * 4;
    int sel = gi / 1310720;
    int off = gi - sel * 1310720;
    const float* src = sel == 0 ? qW : (sel == 1 ? kW : vW);
    float4 vv = *(const float4*)(src + off);
    int h = off / 262144, rest = off - h * 262144;
    ushort4 o;
    o.x = f2bf(vv.x); o.y = f2bf(vv.y); o.z = f2bf(vv.z); o.w = f2bf(vv.w);
    *(ushort4*)(Wb + (size_t)(h * 3 + sel) * 262144 + rest) = o;
  } else if (bid < 9280) {
    int idx8 = (bid - 8960) * 256 + t;
    int e0 = idx8 * 8;
    int c0 = e0 & 511, m = (e0 >> 9) & 255, h = e0 >> 17;
    ushort8 o;
#pragma unroll
    for (int e = 0; e < 8; ++e) {
      int c = c0 + e;
      o[e] = f2bf(relH[((size_t)h * 512 + c) * 16 + (m >> 4)] +
                  relW[((size_t)h * 512 + c) * 16 + (m & 15)]);
    }
    *(ushort8*)(posb + e0) = o;
  } else {
    int o = (bid - 9280) * 256 + t;   // < 512
    float sf = fg[o] * rsqrtf(fv[o] + EPSN);
    float c1 = fb[o] - fm[o] * sf;
    float st = tg[o] * rsqrtf(tv[o] + EPSN);
    float c2 = tb[o] - tm[o] * st;
    bnp[o] = make_float4(sf, c1, st, c2);
  }
}

// ---------------------------------------------------------------------------
// k_qkv3: BM=128 x BN=256, BK=32, 8 waves (2M x 4N, per-wave 64x64, acc=64),
// ring-3 LDS (72KB), counted vmcnt(6), 2 blocks/CU. (R6/R8-proven.)
// ---------------------------------------------------------------------------
__global__ __launch_bounds__(512, 4) void k_qkv3(const ushort* __restrict__ Wb,
                                                 const ushort* __restrict__ xT,
                                                 const ushort* __restrict__ posb,
                                                 const float* __restrict__ qB,
                                                 const float* __restrict__ kB,
                                                 const float* __restrict__ vB,
                                                 ushort* __restrict__ qT,
                                                 ushort* __restrict__ kpT,
                                                 ushort* __restrict__ vv) {
  extern __shared__ ushort ls[];   // 72KB: A ring 3x8KB at 0, B ring 3x16KB at 12288
  const int t = threadIdx.x, lane = t & 63;
  const int w = t >> 6, wm = w >> 2, wn = w & 3, g = lane >> 4, l = lane & 15;
  int bid = blockIdx.x;
  bid = (bid & 7) * 240 + (bid >> 3);            // 1920 = 8*240 bijective
  const int h = bid / 384;
  const int r = bid % 384;

  const ushort* Ag;
  const ushort* Bg;
  const bool partA = r < 256;
  int pt = 0, nt = 0, mt = 0, ntv = 0;
  if (partA) {
    pt = r >> 2; nt = r & 3;
    Ag = xT + ((size_t)h * 8192 + pt * 128) * 512;
    Bg = Wb + ((size_t)(h * 3 + (nt >> 1)) * 512 + (nt & 1) * 256) * 512;
  } else {
    const int r2 = r - 256;
    mt = r2 >> 5; ntv = r2 & 31;
    Ag = Wb + ((size_t)(h * 3 + 2) * 512 + mt * 128) * 512;
    Bg = xT + ((size_t)h * 8192 + ntv * 256) * 512;
  }

  f32x4 acc[4][4];
#pragma unroll
  for (int i = 0; i < 4; ++i)
#pragma unroll
    for (int j = 0; j < 4; ++j) acc[i][j] = f32x4{0.f, 0.f, 0.f, 0.f};

#define QKV_STAGE(tt, slot)                                                    \
  {                                                                            \
    const int kb_ = (tt) * 32;                                                 \
    ushort* sa_ = ls + (slot) * 4096;                                          \
    ushort* sb_ = ls + 12288 + (slot) * 8192;                                  \
    {                                                                          \
      int q_ = t;                                                              \
      int row_ = q_ >> 2, s4_ = q_ & 3;                                        \
      int src_ = s4_ ^ ((row_ ^ (row_ >> 2)) & 3);                             \
      gld16(Ag + (size_t)row_ * 512 + kb_ + src_ * 8, sa_ + q_ * 8);           \
    }                                                                          \
    _Pragma("unroll")                                                          \
    for (int p_ = 0; p_ < 2; ++p_) {                                           \
      int q_ = p_ * 512 + t;                                                   \
      int row_ = q_ >> 2, s4_ = q_ & 3;                                        \
      int src_ = s4_ ^ ((row_ ^ (row_ >> 2)) & 3);                             \
      gld16(Bg + (size_t)row_ * 512 + kb_ + src_ * 8, sb_ + q_ * 8);           \
    }                                                                          \
  }

#define QKV_COMPUTE(slot)                                                      \
  {                                                                            \
    ushort* sa_ = ls + (slot) * 4096;                                          \
    ushort* sb_ = ls + 12288 + (slot) * 8192;                                  \
    bf16x8 af[4], bfv[4];                                                      \
    _Pragma("unroll")                                                          \
    for (int j_ = 0; j_ < 4; ++j_) {                                           \
      int rb_ = wn * 64 + j_ * 16 + l;                                         \
      int sb2_ = g ^ ((rb_ ^ (rb_ >> 2)) & 3);                                 \
      bfv[j_] = *(const bf16x8*)(sb_ + rb_ * 32 + sb2_ * 8);                   \
    }                                                                          \
    _Pragma("unroll")                                                          \
    for (int i_ = 0; i_ < 4; ++i_) {                                           \
      int ra_ = wm * 64 + i_ * 16 + l;                                         \
      int sa2_ = g ^ ((ra_ ^ (ra_ >> 2)) & 3);                                 \
      af[i_] = *(const bf16x8*)(sa_ + ra_ * 32 + sa2_ * 8);                    \
    }                                                                          \
    asm volatile("s_waitcnt lgkmcnt(0)" ::: "memory");                         \
    __builtin_amdgcn_sched_barrier(0);                                         \
    __builtin_amdgcn_s_setprio(1);                                             \
    _Pragma("unroll")                                                          \
    for (int i_ = 0; i_ < 4; ++i_)                                             \
      _Pragma("unroll")                                                        \
      for (int j_ = 0; j_ < 4; ++j_)                                           \
        acc[i_][j_] = __builtin_amdgcn_mfma_f32_16x16x32_bf16(af[i_], bfv[j_], \
                                                              acc[i_][j_], 0, 0, 0); \
    __builtin_amdgcn_s_setprio(0);                                             \
  }

  QKV_STAGE(0, 0);
  QKV_STAGE(1, 1);
  for (int tt = 0; tt < 16; ++tt) {
    __builtin_amdgcn_s_barrier();            // all waves done with slot (tt+2)%3
    if (tt < 14) { QKV_STAGE(tt + 2, (tt + 2) % 3); }
    __builtin_amdgcn_sched_barrier(0);
    if (tt < 14)       asm volatile("s_waitcnt vmcnt(6)" ::: "memory");
    else if (tt == 14) asm volatile("s_waitcnt vmcnt(3)" ::: "memory");
    else               asm volatile("s_waitcnt vmcnt(0)" ::: "memory");
    __builtin_amdgcn_s_barrier();            // everyone's stage(tt) landed
    __builtin_amdgcn_sched_barrier(0);
    QKV_COMPUTE(tt % 3);
  }
  __syncthreads();   // loop fully done before LDS reuse as C-bounce

  // C-bounce: 2 rounds of 64 rows, pad 260
  ushort(*Cs)[260] = (ushort(*)[260])ls;     // 64 x 260 x 2B = 33.3KB
  if (partA) {
    const bool isq = nt < 2;
    const float* bias = (isq ? qB : kB) + (size_t)h * 512 + (nt & 1) * 256;
    ushort* dst = isq ? qT : kpT;
    float bj[4];
#pragma unroll
    for (int j = 0; j < 4; ++j) bj[j] = bias[wn * 64 + j * 16 + l];
#pragma unroll
    for (int R = 0; R < 2; ++R) {
      if (wm == R) {
#pragma unroll
        for (int i = 0; i < 4; ++i)
#pragma unroll
          for (int j = 0; j < 4; ++j)
#pragma unroll
            for (int rr = 0; rr < 4; ++rr)
              Cs[i * 16 + g * 4 + rr][wn * 64 + j * 16 + l] = f2bf(acc[i][j][rr] + bj[j]);
      }
      __syncthreads();
#pragma unroll
      for (int it = 0; it < 4; ++it) {
        int lin = it * 512 + t;
        int row = lin >> 5, cc8 = (lin & 31) * 8;
        int pglob = pt * 128 + R * 64 + row;
        ushort8 cv = *(const ushort8*)&Cs[row][cc8];
        if (!isq) {
          ushort8 pv = *(const ushort8*)(posb + ((size_t)h * 256 + (pglob & 255)) * 512 +
                                         (nt & 1) * 256 + cc8);
#pragma unroll
          for (int e = 0; e < 8; ++e) cv[e] = f2bf(bf2f(cv[e]) + bf2f(pv[e]));
        }
        *(ushort8*)(dst + ((size_t)h * 8192 + pglob) * 512 + (nt & 1) * 256 + cc8) = cv;
      }
      if (R == 0) __syncthreads();
    }
  } else {
    const float* bias = vB + (size_t)h * 512 + mt * 128;
#pragma unroll
    for (int R = 0; R < 2; ++R) {
      if (wm == R) {
#pragma unroll
        for (int i = 0; i < 4; ++i) {
          float4 b4 = *(const float4*)(bias + R * 64 + i * 16 + g * 4);
#pragma unroll
          for (int j = 0; j < 4; ++j)
#pragma unroll
            for (int rr = 0; rr < 4; ++rr)
              Cs[i * 16 + g * 4 + rr][wn * 64 + j * 16 + l] =
                  f2bf(acc[i][j][rr] + ((const float*)&b4)[rr]);
        }
      }
      __syncthreads();
#pragma unroll
      for (int it = 0; it < 4; ++it) {
        int lin = it * 512 + t;
        int row = lin >> 5, cc8 = (lin & 31) * 8;
        int og = mt * 128 + R * 64 + row;
        ushort8 cv = *(const ushort8*)&Cs[row][cc8];
        *(ushort8*)(vv + (((size_t)(h * 32 + ntv)) * 512 + og) * 256 + cc8) = cv;
      }
      if (R == 0) __syncthreads();
    }
  }
#undef QKV_STAGE
#undef QKV_COMPUTE
}

// ---------------------------------------------------------------------------
// k_attn: fused energy+softmax (640) | cvtWconv (1024)
// ---------------------------------------------------------------------------
__global__ __launch_bounds__(256) void k_attn(const ushort* __restrict__ qT,
                                              const ushort* __restrict__ kpT,
                                              const float* __restrict__ fusW,
                                              ushort* __restrict__ attn,
                                              ushort* __restrict__ Wconv) {
  __shared__ ushort sm[20480];   // As 4096 | Bs 16384 ; reused as P[64][260]
  __shared__ float red[4][64];
  __shared__ float comb[64];
  int bid = blockIdx.x;
  const int t = threadIdx.x;
  if (bid >= 640) {
    int p = (bid - 640) * 256 + t;
    const float* src = fusW + (size_t)p * 9;
    float vv[9];
#pragma unroll
    for (int s = 0; s < 9; ++s) vv[s] = src[s];
#pragma unroll
    for (int s = 0; s < 9; ++s) Wconv[(size_t)s * 262144 + p] = f2bf(vv[s]);
    return;
  }
  bid = (bid & 7) * 80 + (bid >> 3);              // 640 = 8*80
  const int rt = bid & 3;
  const int hb = bid >> 2;
  ushort* As = sm;
  ushort* Bs = sm + 4096;
  const ushort* Ag = qT + ((size_t)hb * 256 + rt * 64) * 512;
  const ushort* Bg = kpT + (size_t)hb * 256 * 512;
  const int lane = t & 63, w = t >> 6, g = lane >> 4, l = lane & 15;

  f32x4 acc[4][4];
#pragma unroll
  for (int i = 0; i < 4; ++i)
#pragma unroll
    for (int j = 0; j < 4; ++j) acc[i][j] = f32x4{0.f, 0.f, 0.f, 0.f};

  for (int kt = 0; kt < 8; ++kt) {
    const int kbase = kt * 64;
#pragma unroll
    for (int p = 0; p < 2; ++p) {
      int q = p * 256 + t;
      int row = q >> 3, slot = q & 7, srcs = slot ^ (row & 7);
      gld16(Ag + (size_t)row * 512 + kbase + srcs * 8, As + (p * 256 + w * 64) * 8);
    }
#pragma unroll
    for (int p = 0; p < 8; ++p) {
      int q = p * 256 + t;
      int row = q >> 3, slot = q & 7, srcs = slot ^ (row & 7);
      gld16(Bg + (size_t)row * 512 + kbase + srcs * 8, Bs + (p * 256 + w * 64) * 8);
    }
    __syncthreads();
#pragma unroll
    for (int kk = 0; kk < 2; ++kk) {
      bf16x8 af[4], bfv[4];
#pragma unroll
      for (int i = 0; i < 4; ++i) {
        int ra = i * 16 + l;
        int sa = (kk * 4 + g) ^ (ra & 7);
        af[i] = *(const bf16x8*)(As + ra * 64 + sa * 8);
        int rb = w * 64 + i * 16 + l;
        int sb = (kk * 4 + g) ^ (rb & 7);
        bfv[i] = *(const bf16x8*)(Bs + rb * 64 + sb * 8);
      }
#pragma unroll
      for (int i = 0; i < 4; ++i)
#pragma unroll
        for (int j = 0; j < 4; ++j)
          acc[i][j] = __builtin_amdgcn_mfma_f32_16x16x32_bf16(af[i], bfv[j], acc[i][j], 0, 0, 0);
    }
    __syncthreads();
  }

#pragma unroll
  for (int i = 0; i < 4; ++i)
#pragma unroll
    for (int rr = 0; rr < 4; ++rr) {
      float v = fmaxf(fmaxf(acc[i][0][rr], acc[i][1][rr]), fmaxf(acc[i][2][rr], acc[i][3][rr]));
#pragma unroll
      for (int m = 1; m < 16; m <<= 1) v = fmaxf(v, __shfl_xor(v, m));
      if (l == 0) red[w][i * 16 + g * 4 + rr] = v;
    }
  __syncthreads();
  if (t < 64) comb[t] = fmaxf(fmaxf(red[0][t], red[1][t]), fmaxf(red[2][t], red[3][t]));
  __syncthreads();
#pragma unroll
  for (int i = 0; i < 4; ++i)
#pragma unroll
    for (int rr = 0; rr < 4; ++rr) {
      float mx = comb[i * 16 + g * 4 + rr];
      float s = 0.f;
#pragma unroll
      for (int j = 0; j < 4; ++j) {
        float e = expf(acc[i][j][rr] - mx);
        acc[i][j][rr] = e;
        s += e;
      }
#pragma unroll
      for (int m = 1; m < 16; m <<= 1) s += __shfl_xor(s, m);
      if (l == 0) red[w][i * 16 + g * 4 + rr] = s;
    }
  __syncthreads();
  if (t < 64) comb[t] = red[0][t] + red[1][t] + red[2][t] + red[3][t];
  __syncthreads();
  ushort(*P)[260] = (ushort(*)[260])sm;
#pragma unroll
  for (int i = 0; i < 4; ++i)
#pragma unroll
    for (int rr = 0; rr < 4; ++rr) {
      int row = i * 16 + g * 4 + rr;
      float inv = 1.f / comb[row];
#pragma unroll
      for (int j = 0; j < 4; ++j)
        P[row][w * 64 + j * 16 + l] = f2bf(acc[i][j][rr] * inv);
    }
  __syncthreads();
  ushort* Arow = attn + (size_t)hb * 65536 + (size_t)rt * 16384;
#pragma unroll
  for (int it = 0; it < 8; ++it) {
    int lin = it * 256 + t;
    int row = lin >> 5, c8 = (lin & 31) * 8;
    ushort8 cv = *(const ushort8*)&P[row][c8];
    *(ushort8*)(Arow + (size_t)row * 256 + c8) = cv;
  }
}

// ---------------------------------------------------------------------------
// k_pv: OT[n][c] = sum_m attn[n][m] * vv[c][m]. 128x128, BK=32, ring-3,
// counted vmcnt(8), 4 waves. (R6/R8-proven.)
// ---------------------------------------------------------------------------
__global__ __launch_bounds__(256, 4) void k_pv(const ushort* __restrict__ attn,
                                               const ushort* __restrict__ vv,
                                               ushort* __restrict__ OT) {
  __shared__ ushort pls[24576];   // 48KB: A ring 3x4096, B ring 3x4096 @12288
  const int t = threadIdx.x, lane = t & 63, w = t >> 6;
  const int wr = w >> 1, wc = w & 1, g = lane >> 4, l = lane & 15;
  int bid = blockIdx.x;
  bid = (bid & 7) * 160 + (bid >> 3);             // 1280 = 8*160
  const int nt = bid & 3; bid >>= 2;
  const int mt = bid & 1; bid >>= 1;
  const size_t hb = (size_t)bid;
  const ushort* Ag = attn + (hb * 256 + mt * 128) * 256;
  const ushort* Bg = vv + (hb * 512 + nt * 128) * 256;

  f32x4 acc[4][4];
#pragma unroll
  for (int i = 0; i < 4; ++i)
#pragma unroll
    for (int j = 0; j < 4; ++j) acc[i][j] = f32x4{0.f, 0.f, 0.f, 0.f};

#define PV_STAGE(tt, slot)                                                     \
  {                                                                            \
    const int kb_ = (tt) * 32;                                                 \
    ushort* sa_ = pls + (slot) * 4096;                                         \
    ushort* sb_ = pls + 12288 + (slot) * 4096;                                 \
    _Pragma("unroll")                                                          \
    for (int p_ = 0; p_ < 2; ++p_) {                                           \
      int q_ = p_ * 256 + t;                                                   \
      int row_ = q_ >> 2, s4_ = q_ & 3;                                        \
      int src_ = s4_ ^ ((row_ ^ (row_ >> 2)) & 3);                             \
      gld16(Ag + (size_t)row_ * 256 + kb_ + src_ * 8, sa_ + q_ * 8);           \
      gld16(Bg + (size_t)row_ * 256 + kb_ + src_ * 8, sb_ + q_ * 8);           \
    }                                                                          \
  }

#define PV_COMPUTE(slot)                                                       \
  {                                                                            \
    ushort* sa_ = pls + (slot) * 4096;                                         \
    ushort* sb_ = pls + 12288 + (slot) * 4096;                                 \
    bf16x8 af[4], bfv[4];                                                      \
    _Pragma("unroll")                                                          \
    for (int i_ = 0; i_ < 4; ++i_) {                                           \
      int ra_ = wr * 64 + i_ * 16 + l;                                         \
      int sa2_ = g ^ ((ra_ ^ (ra_ >> 2)) & 3);                                 \
      af[i_] = *(const bf16x8*)(sa_ + ra_ * 32 + sa2_ * 8);                    \
      int rb_ = wc * 64 + i_ * 16 + l;                                         \
      int sb2_ = g ^ ((rb_ ^ (rb_ >> 2)) & 3);                                 \
      bfv[i_] = *(const bf16x8*)(sb_ + rb_ * 32 + sb2_ * 8);                   \
    }                                                                          \
    asm volatile("s_waitcnt lgkmcnt(0)" ::: "memory");                         \
    __builtin_amdgcn_sched_barrier(0);                                         \
    __builtin_amdgcn_s_setprio(1);                                             \
    _Pragma("unroll")                                                          \
    for (int i_ = 0; i_ < 4; ++i_)                                             \
      _Pragma("unroll")                                                        \
      for (int j_ = 0; j_ < 4; ++j_)                                           \
        acc[i_][j_] = __builtin_amdgcn_mfma_f32_16x16x32_bf16(af[i_], bfv[j_], \
                                                              acc[i_][j_], 0, 0, 0); \
    __builtin_amdgcn_s_setprio(0);                                             \
  }

  PV_STAGE(0, 0);
  PV_STAGE(1, 1);
  for (int tt = 0; tt < 8; ++tt) {
    __builtin_amdgcn_s_barrier();
    if (tt < 6) { PV_STAGE(tt + 2, (tt + 2) % 3); }
    __builtin_amdgcn_sched_barrier(0);
    if (tt < 6)       asm volatile("s_waitcnt vmcnt(8)" ::: "memory");
    else if (tt == 6) asm volatile("s_waitcnt vmcnt(4)" ::: "memory");
    else              asm volatile("s_waitcnt vmcnt(0)" ::: "memory");
    __builtin_amdgcn_s_barrier();
    __builtin_amdgcn_sched_barrier(0);
    PV_COMPUTE(tt % 3);
  }
  __syncthreads();

  ushort(*Cs)[148] = (ushort(*)[148])pls;   // 128 x 148 x 2B = 37.9KB
#pragma unroll
  for (int i = 0; i < 4; ++i)
#pragma unroll
    for (int j = 0; j < 4; ++j)
#pragma unroll
      for (int rr = 0; rr < 4; ++rr)
        Cs[wr * 64 + i * 16 + g * 4 + rr][wc * 64 + j * 16 + l] = f2bf(acc[i][j][rr]);
  __syncthreads();
#pragma unroll
  for (int it = 0; it < 8; ++it) {
    int lin = it * 256 + t;
    int row = lin >> 4, cc = (lin & 15) * 8;
    ushort8 cv = *(const ushort8*)&Cs[row][cc];
    *(ushort8*)(OT + (hb * 256 + mt * 128 + row) * 512 + nt * 128 + cc) = cv;
  }
#undef PV_STAGE
#undef PV_COMPUTE
}

// ---------------------------------------------------------------------------
// k_weights: wave-per-pixel, msw staged once per block in LDS
// ---------------------------------------------------------------------------
__global__ __launch_bounds__(256) void k_weights(const ushort* __restrict__ OT,
                                                 const float* __restrict__ mswW,
                                                 const float* __restrict__ mg,
                                                 const float* __restrict__ mb,
                                                 const float* __restrict__ mm,
                                                 const float* __restrict__ mv,
                                                 ushort* __restrict__ xmsT) {
  __shared__ float msw[10240];
  const int t = threadIdx.x, lane = t & 63, w = t >> 6;
#pragma unroll
  for (int it = 0; it < 10; ++it) {
    int idx = it * 1024 + t * 4;
    *(float4*)(msw + idx) = *(const float4*)(mswW + idx);
  }
  __syncthreads();
  const size_t pix = (size_t)blockIdx.x * 4 + w;
  float o[5][2][4];
#pragma unroll
  for (int h = 0; h < 5; ++h)
#pragma unroll
    for (int hf = 0; hf < 2; ++hf) {
      ushort4 v = *(const ushort4*)(OT + ((size_t)h * 8192 + pix) * 512 + hf * 256 + lane * 4);
      o[h][hf][0] = bf2f(v.x); o[h][hf][1] = bf2f(v.y);
      o[h][hf][2] = bf2f(v.z); o[h][hf][3] = bf2f(v.w);
    }
  float a[4] = {0.f, 0.f, 0.f, 0.f};
#pragma unroll
  for (int j = 0; j < 4; ++j)
#pragma unroll
    for (int h = 0; h < 5; ++h)
#pragma unroll
      for (int hf = 0; hf < 2; ++hf) {
        float4 m4 = *(const float4*)(msw + j * 2560 + h * 512 + hf * 256 + lane * 4);
        a[j] += m4.x * o[h][hf][0] + m4.y * o[h][hf][1] +
                m4.z * o[h][hf][2] + m4.w * o[h][hf][3];
      }
#pragma unroll
  for (int m = 1; m < 64; m <<= 1) {
    a[0] += __shfl_xor(a[0], m); a[1] += __shfl_xor(a[1], m);
    a[2] += __shfl_xor(a[2], m); a[3] += __shfl_xor(a[3], m);
  }
  float wj[4];
#pragma unroll
  for (int j = 0; j < 4; ++j) {
    float val = (a[j] - mm[j]) * (mg[j] * rsqrtf(mv[j] + EPSN)) + mb[j];
    wj[j] = 1.f / (1.f + expf(-val));
  }
#pragma unroll
  for (int hf = 0; hf < 2; ++hf) {
    float r0 = wj[0] * o[0][hf][0] + wj[1] * o[1][hf][0] + wj[2] * o[2][hf][0] + wj[3] * o[3][hf][0] + o[4][hf][0];
    float r1 = wj[0] * o[0][hf][1] + wj[1] * o[1][hf][1] + wj[2] * o[2][hf][1] + wj[3] * o[3][hf][1] + o[4][hf][1];
    float r2 = wj[0] * o[0][hf][2] + wj[1] * o[1][hf][2] + wj[2] * o[2][hf][2] + wj[3] * o[3][hf][2] + o[4][hf][2];
    float r3 = wj[0] * o[0][hf][3] + wj[1] * o[1][hf][3] + wj[2] * o[2][hf][3] + wj[3] * o[3][hf][3] + o[4][hf][3];
    ushort4 pk; pk.x = f2bf(r0); pk.y = f2bf(r1); pk.z = f2bf(r2); pk.w = f2bf(r3);
    *(ushort4*)(xmsT + pix * 512 + hf * 256 + lane * 4) = pk;
  }
}

// ---------------------------------------------------------------------------
// conv3x3 full-K, 512 blocks (o-tile 64, n-tile 128), 256 threads (4 waves,
// per-wave 32o x 64n), fused bn_fus+relu+residual+bn_top+relu -> d_out.
// ---------------------------------------------------------------------------
__global__ __launch_bounds__(256) void k_conv(const ushort* __restrict__ Wconv,
                                              const ushort* __restrict__ xmsT,
                                              const float* __restrict__ x,
                                              const float4* __restrict__ bnp,
                                              float* __restrict__ out) {
  __shared__ ushort As3[3 * 4096];       // 24KB: 3 dx x (64 o x 64 c)
  __shared__ ushort xp[180 * 76];        // 26.7KB (pad 76)
  int bid = blockIdx.x;
  bid = (bid & 7) * 64 + (bid >> 3);              // 512 = 8*64
  const int ntl = bid & 1; bid >>= 1;
  const int mt = bid & 7;  bid >>= 3;             // o-tile of 64
  const int bb = bid;                             // 0..31
  const int y0 = ntl * 8;
  const int t = threadIdx.x, lane = t & 63;
  const int w = t >> 6, wm = w >> 1, wn = w & 1, g = lane >> 4, l = lane & 15;
  f32x4 acc[2][4];
#pragma unroll
  for (int i = 0; i < 2; ++i)
#pragma unroll
    for (int j = 0; j < 4; ++j) acc[i][j] = f32x4{0.f, 0.f, 0.f, 0.f};

  for (int cb = 0; cb < 8; ++cb) {
    __syncthreads();
    for (int u = t; u < 1440; u += 256) {
      int slot = u & 7;
      int xpi = (u >> 3) % 18;
      int rl = u / 144;
      int yg = y0 - 1 + rl, xg = xpi - 1;
      uint4 val = make_uint4(0, 0, 0, 0);
      if (yg >= 0 && yg < 16 && (unsigned)xg < 16u)
        val = *(const uint4*)(xmsT + ((size_t)bb * 256 + yg * 16 + xg) * 512 + cb * 64 + slot * 8);
      *(uint4*)(xp + (rl * 18 + xpi) * 76 + slot * 8) = val;
    }
    for (int dy = 0; dy < 3; ++dy) {
#pragma unroll
      for (int dx = 0; dx < 3; ++dx)
#pragma unroll
        for (int p = 0; p < 2; ++p) {
          int q = p * 256 + t;
          int row = q >> 3, slot = q & 7, srcs = slot ^ (row & 7);
          gld16(Wconv + ((size_t)(dy * 3 + dx) * 512 + mt * 64 + row) * 512 + cb * 64 + srcs * 8,
                As3 + dx * 4096 + q * 8);
        }
      __syncthreads();
#pragma unroll
      for (int dx = 0; dx < 3; ++dx)
#pragma unroll
        for (int kk = 0; kk < 2; ++kk) {
          bf16x8 af[2], bfv[4];
#pragma unroll
          for (int j = 0; j < 4; ++j) {
            int nl = wn * 64 + j * 16 + l;
            int pp = ((nl >> 4) + dy) * 18 + (nl & 15) + dx;
            bfv[j] = *(const bf16x8*)(xp + pp * 76 + (kk * 4 + g) * 8);
          }
#pragma unroll
          for (int i = 0; i < 2; ++i) {
            int ra = wm * 32 + i * 16 + l;
            int sa = (kk * 4 + g) ^ (ra & 7);
            af[i] = *(const bf16x8*)(As3 + dx * 4096 + ra * 64 + sa * 8);
          }
#pragma unroll
          for (int i = 0; i < 2; ++i)
#pragma unroll
            for (int j = 0; j < 4; ++j)
              acc[i][j] = __builtin_amdgcn_mfma_f32_16x16x32_bf16(af[i], bfv[j], acc[i][j], 0, 0, 0);
        }
      __syncthreads();
    }
  }
  // fused epilogue: z = max(acc*sf+c1,0); out = max((z+x)*st+c2, 0)
  const int o0 = mt * 64 + wm * 32;
#pragma unroll
  for (int i = 0; i < 2; ++i)
#pragma unroll
    for (int rr = 0; rr < 4; ++rr) {
      int o = o0 + i * 16 + g * 4 + rr;
      float4 p4 = bnp[o];
#pragma unroll
      for (int j = 0; j < 4; ++j) {
        int n = ntl * 128 + wn * 64 + j * 16 + l;
        size_t idx = ((size_t)bb * 512 + o) * 256 + n;
        float z = fmaxf(acc[i][j][rr] * p4.x + p4.y, 0.f);
        out[idx] = fmaxf((z + x[idx]) * p4.z + p4.w, 0.f);
      }
    }
}

// ---------------------------------------------------------------------------
extern "C" void kernel_launch(void* const* d_in, const int* in_sizes, int n_in,
                              void* d_out, int out_size, void* d_ws, size_t ws_size,
                              hipStream_t stream) {
  const float* x0   = (const float*)d_in[0];
  const float* x1   = (const float*)d_in[1];
  const float* x2   = (const float*)d_in[2];
  const float* x3   = (const float*)d_in[3];
  const float* x4   = (const float*)d_in[4];
  const float* qW   = (const float*)d_in[5];
  const float* qB   = (const float*)d_in[6];
  const float* kW   = (const float*)d_in[7];
  const float* kB   = (const float*)d_in[8];
  const float* vW   = (const float*)d_in[9];
  const float* vB   = (const float*)d_in[10];
  const float* relH = (const float*)d_in[11];
  const float* relW = (const float*)d_in[12];
  const float* mswW = (const float*)d_in[13];
  const float* msg  = (const float*)d_in[14];
  const float* msb  = (const float*)d_in[15];
  const float* msm  = (const float*)d_in[16];
  const float* msv  = (const float*)d_in[17];
  const float* fusW = (const float*)d_in[18];
  const float* fg   = (const float*)d_in[19];
  const float* fb   = (const float*)d_in[20];
  const float* fm   = (const float*)d_in[21];
  const float* fv   = (const float*)d_in[22];
  const float* tg   = (const float*)d_in[23];
  const float* tb   = (const float*)d_in[24];
  const float* tm   = (const float*)d_in[25];
  const float* tv   = (const float*)d_in[26];

  if (ws_size < 180355072ull) return;
  char* ws = (char*)d_ws;
  ushort* xT    = (ushort*)(ws + 0);           // R0 until k_qkv3
  ushort* attn  = (ushort*)(ws + 0);           // R0[0..21MB) after k_qkv3
  ushort* Wconv = (ushort*)(ws + 20971520);    // R0[21..25.7MB) after k_qkv3
  ushort* qT    = (ushort*)(ws + 41943040);    // R1 until k_attn
  ushort* xmsT  = (ushort*)(ws + 41943040);    // R1[0..8.4MB) after k_attn
  ushort* kpT   = (ushort*)(ws + 83886080);    // R2 until k_attn
  ushort* OT    = (ushort*)(ws + 83886080);    // R2 after k_attn
  ushort* vv    = (ushort*)(ws + 125829120);   // R3 until k_pv
  ushort* Wb    = (ushort*)(ws + 167772160);   // R4
  ushort* posb  = (ushort*)(ws + 175636480);   // R4 + 7.5MB (1.25MB)
  float4* bnp   = (float4*)(ws + 176947200);   // 8KB

  hipFuncSetAttribute((const void*)k_qkv3,
                      hipFuncAttributeMaxDynamicSharedMemorySize, 73728);

  k_pre    <<<9282, 256, 0, stream>>>(x0, x1, x2, x3, x4, qW, kW, vW, relH, relW,
                                      fg, fb, fm, fv, tg, tb, tm, tv,
                                      xT, Wb, posb, (float4*)bnp);
  k_qkv3   <<<1920, 512, 73728, stream>>>(Wb, xT, posb, qB, kB, vB, qT, kpT, vv);
  k_attn   <<<1664, 256, 0, stream>>>(qT, kpT, fusW, attn, Wconv);
  k_pv     <<<1280, 256, 0, stream>>>(attn, vv, OT);
  k_weights<<<2048, 256, 0, stream>>>(OT, mswW, msg, msb, msm, msv, xmsT);
  k_conv   <<<512,  256, 0, stream>>>(Wconv, xmsT, x4, bnp, (float*)d_out);
}